// Round 2
// baseline (406.172 us; speedup 1.0000x reference)
//
#include <hip/hip_runtime.h>

// BilinearLayer: out = sigmoid( (E @ Bs_r) @ E^T ) per (b,r)
// B=8 R=8 N=1024 F=256.  All compute in f16 MFMA (16x16x32), fp32 accum.
//
// ws layout (_Float16 elements):
//   wsE   [64][32][1024][8] : E fp16, fragment layout [br][f/8][n][8]   (32 MB)
//   wsBsT [8][32][256][8]   : Bs^T fp16, [r][f/8][g][8]                 (1 MB)
//   wse   [64][32][1024][8] : e fp16, [br][g/8][n][8]                   (32 MB)

typedef float    f32x4 __attribute__((ext_vector_type(4)));
typedef _Float16 f16x8 __attribute__((ext_vector_type(8)));

#define WS_E_OFF   0
#define WS_BST_OFF 16777216
#define WS_e_OFF   17301504

typedef __attribute__((address_space(3))) void  lds_void;
typedef const __attribute__((address_space(1))) void glb_void;
// async global->LDS, 16B per lane; LDS dest must be wave-uniform base + lane*16
#define GLOAD16(gp, lp) __builtin_amdgcn_global_load_lds((glb_void*)(gp), (lds_void*)(lp), 16, 0, 0)

// ---------------- kernel 0: convert via LDS transpose (coalesced both sides) --
__global__ __launch_bounds__(256) void bl_convert(
    const float* __restrict__ E, const float* __restrict__ Bs,
    _Float16* __restrict__ wsE, _Float16* __restrict__ wsBsT) {
  __shared__ _Float16 s[16640];   // E: 32 fc * 520 (64 rows*8 + pad); Bs: 8 * 2056
  int bid = blockIdx.x, t = threadIdx.x;
  if (bid < 1024) {
    // E tile: 64 n-rows x 256 f.  [n][f] fp32 -> [fc][n][8] fp16
    int br = bid >> 4, n0 = (bid & 15) << 6;
    const float* src = E + ((size_t)br << 18) + ((size_t)n0 << 8);
#pragma unroll
    for (int i = 0; i < 8; ++i) {
      int idx = (i << 8) + t;
      int n_l = idx >> 5, fc = idx & 31;          // fc fast -> coalesced 32B reads
      const float* p = src + (n_l << 8) + (fc << 3);
      f32x4 v0 = *(const f32x4*)p;
      f32x4 v1 = *(const f32x4*)(p + 4);
      f16x8 h;
      h[0]=(_Float16)v0[0]; h[1]=(_Float16)v0[1]; h[2]=(_Float16)v0[2]; h[3]=(_Float16)v0[3];
      h[4]=(_Float16)v1[0]; h[5]=(_Float16)v1[1]; h[6]=(_Float16)v1[2]; h[7]=(_Float16)v1[3];
      *(f16x8*)&s[fc * 520 + (n_l << 3)] = h;     // stride 520: 16B-aligned, 4-way max
    }
    __syncthreads();
    _Float16* dst = wsE + ((size_t)br << 18) + (n0 << 3);
#pragma unroll
    for (int i = 0; i < 8; ++i) {
      int idx = (i << 8) + t;
      int fc = idx >> 6, n_l = idx & 63;          // n_l fast -> 1KB contiguous stores
      *(f16x8*)(dst + (fc << 13) + (n_l << 3)) = *(const f16x8*)&s[fc * 520 + (n_l << 3)];
    }
  } else {
    // Bs tile: 64 f-rows x 256 g.  [f][g] fp32 -> [fc][g][8] fp16 (true transpose)
    int b2 = bid - 1024;
    int r = b2 >> 2, f0 = (b2 & 3) << 6;
    const float* src = Bs + (r << 16) + (f0 << 8);
#pragma unroll
    for (int i = 0; i < 8; ++i) {
      int idx = (i << 8) + t;
      int f_l = idx >> 5, gc8 = idx & 31;         // gc8 fast -> coalesced 32B reads
      const float* p = src + (f_l << 8) + (gc8 << 3);
      f32x4 v0 = *(const f32x4*)p;
      f32x4 v1 = *(const f32x4*)(p + 4);
      int base = (f_l >> 3) * 2056 + (gc8 << 6) + (f_l & 7);
      s[base +  0] = (_Float16)v0[0];
      s[base +  8] = (_Float16)v0[1];
      s[base + 16] = (_Float16)v0[2];
      s[base + 24] = (_Float16)v0[3];
      s[base + 32] = (_Float16)v1[0];
      s[base + 40] = (_Float16)v1[1];
      s[base + 48] = (_Float16)v1[2];
      s[base + 56] = (_Float16)v1[3];
    }
    __syncthreads();
    _Float16* dst = wsBsT + (r << 16) + (f0 << 8);  // (f0/8)<<11 == f0<<8
#pragma unroll
    for (int i = 0; i < 8; ++i) {
      int idx = (i << 8) + t;
      int fc_l = idx >> 8, g = idx & 255;         // g fast -> 1KB contiguous stores
      *(f16x8*)(dst + (fc_l << 11) + (g << 3)) = *(const f16x8*)&s[fc_l * 2056 + (g << 3)];
    }
  }
}

// ---------------- kernel 1: e = E @ Bs_r  (fp16 in, fp16 out) ----------------
__global__ __launch_bounds__(256) void bl_gemm1(
    const _Float16* __restrict__ wsE, const _Float16* __restrict__ wsBsT,
    _Float16* __restrict__ wse) {
  __shared__ _Float16 sA[8192];   // [kcl(8)][row(128)][8]
  __shared__ _Float16 sB[8192];
  int bid = blockIdx.x;
  int br = bid >> 4;
  int t  = bid & 15;
  int n0 = (t >> 1) << 7;
  int g0 = (t & 1) << 7;
  int r  = br & 7;
  int tid  = threadIdx.x;
  int lane = tid & 63, wave = tid >> 6;
  int wm = wave >> 1, wn = wave & 1;
  int quad = lane >> 4, l16 = lane & 15;

  const _Float16* aG = wsE   + ((size_t)br << 18) + (n0 << 3);
  const _Float16* bG = wsBsT + (r << 16) + (g0 << 3);

  f32x4 acc[4][4] = {};

  for (int kk = 0; kk < 4; ++kk) {
    __syncthreads();
#pragma unroll
    for (int i = 0; i < 4; ++i) {
      int c = (i << 8) + tid;
      GLOAD16(aG + (((kk << 3) + (c >> 7)) << 13) + ((c & 127) << 3), &sA[c << 3]);
    }
#pragma unroll
    for (int i = 0; i < 4; ++i) {
      int c = (i << 8) + tid;
      GLOAD16(bG + (((kk << 3) + (c >> 7)) << 11) + ((c & 127) << 3), &sB[c << 3]);
    }
    __syncthreads();
#pragma unroll
    for (int ks = 0; ks < 2; ++ks) {
      int kc = (ks << 2) + quad;
      f16x8 af[4], bf[4];
#pragma unroll
      for (int rt = 0; rt < 4; ++rt)
        af[rt] = *(const f16x8*)&sA[((kc << 7) + (wm << 6) + (rt << 4) + l16) << 3];
#pragma unroll
      for (int ct = 0; ct < 4; ++ct)
        bf[ct] = *(const f16x8*)&sB[((kc << 7) + (wn << 6) + (ct << 4) + l16) << 3];
#pragma unroll
      for (int rt = 0; rt < 4; ++rt)
#pragma unroll
        for (int ct = 0; ct < 4; ++ct)
          acc[rt][ct] = __builtin_amdgcn_mfma_f32_16x16x32_f16(af[rt], bf[ct], acc[rt][ct], 0, 0, 0);
    }
  }
  _Float16* eB = wse + ((size_t)br << 18);
#pragma unroll
  for (int rt = 0; rt < 4; ++rt) {
#pragma unroll
    for (int ct = 0; ct < 4; ++ct) {
      int g  = g0 + (wn << 6) + (ct << 4) + l16;
      int gc = g >> 3, gj = g & 7;
#pragma unroll
      for (int i = 0; i < 4; ++i) {
        int n = n0 + (wm << 6) + (rt << 4) + (quad << 2) + i;
        eB[(gc << 13) + (n << 3) + gj] = (_Float16)acc[rt][ct][i];
      }
    }
  }
}

// ---------------- kernel 2: out = sigmoid(e @ E^T) ----------------
__global__ __launch_bounds__(256) void bl_gemm2(
    const _Float16* __restrict__ wse, const _Float16* __restrict__ wsE,
    float* __restrict__ out) {
  __shared__ _Float16 sA[8192];
  __shared__ _Float16 sB[8192];
  int bid = blockIdx.x;
  int br = bid >> 6;
  int t  = bid & 63;
  int n0 = (t >> 3) << 7;
  int m0 = (t & 7) << 7;
  int tid  = threadIdx.x;
  int lane = tid & 63, wave = tid >> 6;
  int wm = wave >> 1, wn = wave & 1;
  int quad = lane >> 4, l16 = lane & 15;

  const _Float16* aG = wse + ((size_t)br << 18) + (n0 << 3);
  const _Float16* bG = wsE + ((size_t)br << 18) + (m0 << 3);

  f32x4 acc[4][4] = {};

  for (int kk = 0; kk < 4; ++kk) {
    __syncthreads();
#pragma unroll
    for (int i = 0; i < 4; ++i) {
      int c = (i << 8) + tid;
      GLOAD16(aG + (((kk << 3) + (c >> 7)) << 13) + ((c & 127) << 3), &sA[c << 3]);
    }
#pragma unroll
    for (int i = 0; i < 4; ++i) {
      int c = (i << 8) + tid;
      GLOAD16(bG + (((kk << 3) + (c >> 7)) << 13) + ((c & 127) << 3), &sB[c << 3]);
    }
    __syncthreads();
#pragma unroll
    for (int ks = 0; ks < 2; ++ks) {
      int kc = (ks << 2) + quad;
      f16x8 af[4], bf[4];
#pragma unroll
      for (int rt = 0; rt < 4; ++rt)
        af[rt] = *(const f16x8*)&sA[((kc << 7) + (wm << 6) + (rt << 4) + l16) << 3];
#pragma unroll
      for (int ct = 0; ct < 4; ++ct)
        bf[ct] = *(const f16x8*)&sB[((kc << 7) + (wn << 6) + (ct << 4) + l16) << 3];
#pragma unroll
      for (int rt = 0; rt < 4; ++rt)
#pragma unroll
        for (int ct = 0; ct < 4; ++ct)
          acc[rt][ct] = __builtin_amdgcn_mfma_f32_16x16x32_f16(af[rt], bf[ct], acc[rt][ct], 0, 0, 0);
    }
  }
  // epilogue: sigmoid -> fp32 nontemporal store, out[br][n][m]
  float* p0 = out + ((size_t)br << 20)
            + ((size_t)(n0 + (wm << 6) + (quad << 2)) << 10)
            + m0 + (wn << 6) + l16;
#pragma unroll
  for (int rt = 0; rt < 4; ++rt) {
#pragma unroll
    for (int ct = 0; ct < 4; ++ct) {
#pragma unroll
      for (int i = 0; i < 4; ++i) {
        float x = acc[rt][ct][i];
        float sg = 1.0f / (1.0f + __expf(-x));
        __builtin_nontemporal_store(sg, p0 + (rt << 14) + (i << 10) + (ct << 4));
      }
    }
  }
}

extern "C" void kernel_launch(void* const* d_in, const int* in_sizes, int n_in,
                              void* d_out, int out_size, void* d_ws, size_t ws_size,
                              hipStream_t stream) {
  const float* E  = (const float*)d_in[0];   // [8,8,1024,256]
  const float* Bs = (const float*)d_in[1];   // [8,256,256]
  _Float16* wsE   = (_Float16*)d_ws + WS_E_OFF;
  _Float16* wsBsT = (_Float16*)d_ws + WS_BST_OFF;
  _Float16* wse   = (_Float16*)d_ws + WS_e_OFF;
  float* out = (float*)d_out;

  bl_convert<<<1056, 256, 0, stream>>>(E, Bs, wsE, wsBsT);
  bl_gemm1<<<1024, 256, 0, stream>>>(wsE, wsBsT, wse);
  bl_gemm2<<<4096, 256, 0, stream>>>(wse, wsE, out);
}